// Round 14
// baseline (3171.499 us; speedup 1.0000x reference)
//
#include <hip/hip_runtime.h>
#include <hip/hip_bf16.h>

typedef __attribute__((ext_vector_type(8))) short short8;
typedef __attribute__((ext_vector_type(4))) float f32x4;

#define B_   16
#define O_   512
#define C_   512
#define T_   4096
#define TP   (T_ + 32)     // padded t extent: 16 zero rows each side
#define KT   5
#define BM   256
#define BN   512
#define BK   32
#define NCHUNK (C_/BK)
#define BGR  33            // B row-groups: 33 x 16 rows x 64B

__device__ __forceinline__ void gload_lds16(const void* g, void* l) {
    __builtin_amdgcn_global_load_lds(
        (const __attribute__((address_space(1))) unsigned int*)g,
        (__attribute__((address_space(3))) unsigned int*)l, 16, 0, 0);
}

#define VMW_(N) asm volatile("s_waitcnt vmcnt(" #N ")" ::: "memory")
#define VMW(N)  VMW_(N)
#define BARR    __builtin_amdgcn_s_barrier()

// ---------------- fused prep: wrepack (blocks 0..5119) + padzero (5120..6143) ----
__global__ void prep_kernel(const float* __restrict__ w,
                            unsigned short* __restrict__ wb,
                            unsigned short* __restrict__ xt) {
    int bid = blockIdx.x;
    if (bid < 5120) {
        int e   = bid * 256 + threadIdx.x;
        int n   = e / (O_ * C_);
        int rem = e % (O_ * C_);
        int o   = rem / C_;
        int c   = rem % C_;
        float v = w[((size_t)o * C_ + c) * KT + n];
        __hip_bfloat16 h = __float2bfloat16(v);
        wb[e] = *reinterpret_cast<unsigned short*>(&h);
    } else {
        int i = (bid - 5120) * 256 + threadIdx.x;
        int b = i / (32 * C_);
        int r = (i / C_) % 32;
        int c = i % C_;
        int tp = (r < 16) ? r : (T_ + r);
        xt[((size_t)b * TP + tp) * C_ + c] = 0;
    }
}

// ---------------- x transpose: x[b][c][t] f32 -> xT[b][16+t][c] bf16 ----------------
__global__ void xtrans_kernel(const float* __restrict__ x, unsigned short* __restrict__ xt) {
    __shared__ float tile[64][65];
    int b  = blockIdx.z;
    int c0 = blockIdx.y * 64;
    int t0 = blockIdx.x * 64;
    const float* xb = x + ((size_t)b * C_ + c0) * T_ + t0;
#pragma unroll
    for (int p = 0; p < 4; ++p) {
        int idx = p * 256 + threadIdx.x;
        int cl = idx >> 4;
        int tj = (idx & 15) << 2;
        float4 v = *reinterpret_cast<const float4*>(xb + (size_t)cl * T_ + tj);
        tile[cl][tj + 0] = v.x;
        tile[cl][tj + 1] = v.y;
        tile[cl][tj + 2] = v.z;
        tile[cl][tj + 3] = v.w;
    }
    __syncthreads();
    unsigned short* xtb = xt + ((size_t)b * TP + 16 + t0) * C_ + c0;
#pragma unroll
    for (int p = 0; p < 2; ++p) {
        int g  = p * 256 + threadIdx.x;
        int tl = g >> 3;
        int cj = (g & 7) << 3;
        unsigned short tmp[8];
#pragma unroll
        for (int i = 0; i < 8; ++i) {
            __hip_bfloat16 h = __float2bfloat16(tile[cj + i][tl]);
            tmp[i] = *reinterpret_cast<unsigned short*>(&h);
        }
        *reinterpret_cast<short8*>(xtb + (size_t)tl * C_ + cj) =
            *reinterpret_cast<const short8*>(tmp);
    }
}

// ---------------- conv-as-GEMM: 256x512 block, 128x128 wave tile, MFMA-bound ratio --
// 8 waves 2M x 4N; acc[8][8] (256 f32 -> AGPRs); grid 256 = 1 block/CU.
// A: single LDS buffer [5 taps][16 rowblocks][512], tap-rolling refill (tap m
//    rewritten for next chunk at phase m+1; WAR-safe: the phase barrier certifies
//    all MFMA-operand reads of that tap completed).
// B: double-buffered [2][33][512], R9's proven layout/swizzle, prefetch ph0-1 only.
// Phase p: {counted vmcnt; read tap p+1 frags -> other reg set; barrier;
//           refill/prefetch issues; MFMA tap p}. Uniform 3-phase issue->consume
//           gap => vmcnt allows exactly the last 2 phases' issues: 4/6/9/7/4.
#define LDAB(AS, BS, TAP, BB)                                               \
    _Pragma("unroll")                                                       \
    for (int mi = 0; mi < 8; ++mi)                                          \
        AS[mi] = *reinterpret_cast<const short8*>(                          \
            &a_lds[((TAP) * 16 + wm8 + mi) * 512 + lane * 8]);              \
    _Pragma("unroll")                                                       \
    for (int ni = 0; ni < 8; ++ni) {                                        \
        int row_ = rbase + ni * 16 - (TAP);                                 \
        int off_ = row_ * 32 + ((lg ^ ((row_ >> 1) & 3)) << 3);             \
        BS[ni] = *reinterpret_cast<const short8*>(&b_lds[BB][off_]);        \
    }

#define MFM(AS, BS)                                                         \
    __builtin_amdgcn_s_setprio(1);                                          \
    _Pragma("unroll")                                                       \
    for (int mi = 0; mi < 8; ++mi)                                          \
        _Pragma("unroll")                                                   \
        for (int ni = 0; ni < 8; ++ni)                                      \
            acc[mi][ni] = __builtin_amdgcn_mfma_f32_16x16x32_bf16(          \
                AS[mi], BS[ni], acc[mi][ni], 0, 0, 0);                      \
    __builtin_amdgcn_s_setprio(0);

#define RFA(T, CO)                                                          \
    gload_lds16(ag + (size_t)((T) * O_ + wid * 16) * C_ + (CO),             \
                &a_lds[((T) * 16 + wid) * 512]);                            \
    gload_lds16(ag + (size_t)((T) * O_ + (wid + 8) * 16) * C_ + (CO),       \
                &a_lds[((T) * 16 + wid + 8) * 512]);

#define PFB0(CO, NB)                                                        \
    gload_lds16(bg + (size_t)(wid * 16) * C_ + (CO), &b_lds[NB][wid * 512]);\
    gload_lds16(bg + (size_t)((wid + 8) * 16) * C_ + (CO),                  \
                &b_lds[NB][(wid + 8) * 512]);

#define PFB1(CO, NB)                                                        \
    gload_lds16(bg + (size_t)((wid + 16) * 16) * C_ + (CO),                 \
                &b_lds[NB][(wid + 16) * 512]);                              \
    gload_lds16(bg + (size_t)((wid + 24) * 16) * C_ + (CO),                 \
                &b_lds[NB][(wid + 24) * 512]);                              \
    gload_lds16(bg + (size_t)(je * 16) * C_ + (CO), &b_lds[NB][je * 512]);

// main-chunk: issues/phase = ph0:4, ph1:5, ph2:2, ph3:2, ph4:2
// vmcnt(p) = issues of prev 2 phases: 4, 6, 9, 7, 4.
#define CHUNK_MAIN(P, CH)                                                   \
    {                                                                       \
        const int c0v = (CH) * BK, c1v = ((CH) + 1) * BK;                   \
        const int cb = (CH) & 1, nb = cb ^ 1;                               \
        VMW(4); LDAB(af[(P+1)&1], bf[(P+1)&1], 1, cb) BARR;                 \
        RFA(4, c0v) PFB0(c1v, nb) MFM(af[(P)&1], bf[(P)&1])                 \
        VMW(6); LDAB(af[(P)&1], bf[(P)&1], 2, cb) BARR;                     \
        RFA(0, c1v) PFB1(c1v, nb) MFM(af[(P+1)&1], bf[(P+1)&1])             \
        VMW(9); LDAB(af[(P+1)&1], bf[(P+1)&1], 3, cb) BARR;                 \
        RFA(1, c1v) MFM(af[(P)&1], bf[(P)&1])                               \
        VMW(7); LDAB(af[(P)&1], bf[(P)&1], 4, cb) BARR;                     \
        RFA(2, c1v) MFM(af[(P+1)&1], bf[(P+1)&1])                           \
        VMW(4); LDAB(af[(P+1)&1], bf[(P+1)&1], 0, nb) BARR;                 \
        RFA(3, c1v) MFM(af[(P)&1], bf[(P)&1])                               \
    }

// last chunk: only ph0's RFA(4, c0) runs; drain 4/4/2/0; no next-tap read at ph4.
#define CHUNK_LAST(P, CH)                                                   \
    {                                                                       \
        const int c0v = (CH) * BK;                                          \
        const int cb = (CH) & 1;                                            \
        VMW(4); LDAB(af[(P+1)&1], bf[(P+1)&1], 1, cb) BARR;                 \
        RFA(4, c0v) MFM(af[(P)&1], bf[(P)&1])                               \
        VMW(4); LDAB(af[(P)&1], bf[(P)&1], 2, cb) BARR;                     \
        MFM(af[(P+1)&1], bf[(P+1)&1])                                       \
        VMW(2); LDAB(af[(P+1)&1], bf[(P+1)&1], 3, cb) BARR;                 \
        MFM(af[(P)&1], bf[(P)&1])                                           \
        VMW(0); LDAB(af[(P)&1], bf[(P)&1], 4, cb) BARR;                     \
        MFM(af[(P+1)&1], bf[(P+1)&1])                                       \
        BARR; MFM(af[(P)&1], bf[(P)&1])                                     \
    }

__global__ __launch_bounds__(512, 1) void conv_gemm_kernel(
        const unsigned short* __restrict__ wb,
        const unsigned short* __restrict__ xt,
        const float* __restrict__ bias,
        float* __restrict__ out) {
    __shared__ unsigned short a_lds[KT * 16 * 512];   // 81920 B, single-buf, tap-rolling
    __shared__ unsigned short b_lds[2][BGR * 512];    // 2 x 33792 B

    // XCD-aware bijective swizzle (256 blocks): o-tile innermost so the 2
    // o-tiles sharing a B-panel are consecutive on one XCD.
    int bid = blockIdx.x;
    int swz = (bid & 7) * 32 + (bid >> 3);
    int o0  = (swz & 1) * BM;
    int t0  = ((swz >> 1) & 7) * BN;
    int b   = swz >> 4;

    int tid  = threadIdx.x;
    int lane = tid & 63;
    int wid  = tid >> 6;       // 0..7
    int wm   = wid >> 2;       // 0..1  (m)
    int wn   = wid & 3;        // 0..3  (n)
    int lr   = lane & 15;
    int lg   = lane >> 4;
    int wm8  = wm * 8;
    int rbase = wn * 128 + lr + 4;             // B row base (tap 0, ni 0)
    int je   = (wid == 0) ? 32 : (wid + 24);   // 3rd PFB1 slot (dup for wid>0)

    f32x4 acc[8][8];
#pragma unroll
    for (int mi = 0; mi < 8; ++mi)
#pragma unroll
        for (int ni = 0; ni < 8; ++ni)
            acc[mi][ni] = (f32x4)0.0f;

    // per-lane global staging bases (R9-proven patterns)
    const unsigned short* ag = wb + (size_t)(o0 + lr) * C_ + lg * 8;
    int c8 = (lane & 3) ^ ((lane >> 3) & 3);
    const unsigned short* bg = xt + ((size_t)b * TP + (t0 + 14 + (lane >> 2))) * C_ + c8 * 8;

    short8 af[2][8], bf[2][8];

    // ---- prologue: stage A taps 0-3 (frags 0-63) + B chunk 0 (33 groups)
#pragma unroll
    for (int k = 0; k < 8; ++k) {
        int f = wid + 8 * k;                   // 0..63 : taps 0..3
        gload_lds16(ag + (size_t)((f >> 4) * O_ + (f & 15) * 16) * C_,
                    &a_lds[f * 512]);
    }
#pragma unroll
    for (int k = 0; k < 5; ++k) {
        int j = wid + 8 * k;
        if (j < BGR)
            gload_lds16(bg + (size_t)(j * 16) * C_, &b_lds[0][j * 512]);
    }
    VMW(0);
    BARR;
    LDAB(af[0], bf[0], 0, 0)                   // tap 0 of chunk 0 into set 0

#pragma unroll 1
    for (int cp = 0; cp < 7; ++cp) {
        CHUNK_MAIN(0, 2 * cp);
        CHUNK_MAIN(1, 2 * cp + 1);
    }
    CHUNK_MAIN(0, 14);
    CHUNK_LAST(1, 15);

    // ---- epilogue: C/D layout col=lane&15, row=(lane>>4)*4+reg
#pragma unroll
    for (int mi = 0; mi < 8; ++mi) {
#pragma unroll
        for (int ni = 0; ni < 8; ++ni) {
            int orow = o0 + wm * 128 + mi * 16 + lg * 4;
            int tcol = t0 + wn * 128 + ni * 16 + lr;
#pragma unroll
            for (int r = 0; r < 4; ++r) {
                out[((size_t)b * O_ + orow + r) * T_ + tcol] =
                    acc[mi][ni][r] + bias[orow + r];
            }
        }
    }
}

extern "C" void kernel_launch(void* const* d_in, const int* in_sizes, int n_in,
                              void* d_out, int out_size, void* d_ws, size_t ws_size,
                              hipStream_t stream) {
    const float* x    = (const float*)d_in[0];
    const float* w    = (const float*)d_in[1];
    const float* bias = (const float*)d_in[2];
    float* out        = (float*)d_out;

    unsigned short* wb  = (unsigned short*)d_ws;            // 2.62 MB
    unsigned short* xtp = wb + (size_t)KT * O_ * C_;        // 16*4128*512 bf16 = 67.7 MB

    prep_kernel<<<6144, 256, 0, stream>>>(w, wb, xtp);
    xtrans_kernel<<<dim3(T_ / 64, C_ / 64, B_), 256, 0, stream>>>(x, xtp);
    conv_gemm_kernel<<<256, 512, 0, stream>>>(wb, xtp, bias, out);
}

// Round 15
// 185.580 us; speedup vs baseline: 17.0896x; 17.0896x over previous
//
#include <hip/hip_runtime.h>
#include <hip/hip_bf16.h>

typedef __attribute__((ext_vector_type(8))) short short8;
typedef __attribute__((ext_vector_type(4))) float f32x4;

#define B_   16
#define O_   512
#define C_   512
#define T_   4096
#define TP   (T_ + 32)     // padded t extent: 16 zero rows each side
#define KT   5
#define BM   128
#define BN   512
#define BK   32
#define NCHUNK (C_/BK)
#define AFR  40            // A fragments: 5 taps x 8 rowblocks, 1024B each
#define BGR  33            // B row-groups: 33 x 16 rows x 64B

__device__ __forceinline__ void gload_lds16(const void* g, void* l) {
    __builtin_amdgcn_global_load_lds(
        (const __attribute__((address_space(1))) unsigned int*)g,
        (__attribute__((address_space(3))) unsigned int*)l, 16, 0, 0);
}

// ---------------- fused pre-pass: xtrans (0..8191) + wrepack (..13311) + padzero ----
// xtrans: x[b][c][t] f32 -> xT[b][16+t][c] bf16 (64x64 tiles via padded LDS)
// wrepack: w[o][c][n] f32 -> Wb[n][o][c] bf16
// padzero: zero rows [0,16) and [T+16,T+32) of each batch's xT
__global__ void pre_kernel(const float* __restrict__ x,
                           const float* __restrict__ w,
                           unsigned short* __restrict__ wb,
                           unsigned short* __restrict__ xt) {
    int bid = blockIdx.x;
    if (bid < 8192) {
        __shared__ float tile[64][65];
        int t0 = (bid & 63) * 64;
        int c0 = ((bid >> 6) & 7) * 64;
        int b  = bid >> 9;
        const float* xb = x + ((size_t)b * C_ + c0) * T_ + t0;
#pragma unroll
        for (int p = 0; p < 4; ++p) {
            int idx = p * 256 + threadIdx.x;
            int cl = idx >> 4;
            int tj = (idx & 15) << 2;
            float4 v = *reinterpret_cast<const float4*>(xb + (size_t)cl * T_ + tj);
            tile[cl][tj + 0] = v.x;
            tile[cl][tj + 1] = v.y;
            tile[cl][tj + 2] = v.z;
            tile[cl][tj + 3] = v.w;
        }
        __syncthreads();
        unsigned short* xtb = xt + ((size_t)b * TP + 16 + t0) * C_ + c0;
#pragma unroll
        for (int p = 0; p < 2; ++p) {
            int g  = p * 256 + threadIdx.x;
            int tl = g >> 3;
            int cj = (g & 7) << 3;
            unsigned short tmp[8];
#pragma unroll
            for (int i = 0; i < 8; ++i) {
                __hip_bfloat16 h = __float2bfloat16(tile[cj + i][tl]);
                tmp[i] = *reinterpret_cast<unsigned short*>(&h);
            }
            *reinterpret_cast<short8*>(xtb + (size_t)tl * C_ + cj) =
                *reinterpret_cast<const short8*>(tmp);
        }
    } else if (bid < 8192 + 5120) {
        int e   = (bid - 8192) * 256 + threadIdx.x;   // e < 5*512*512 exactly
        int n   = e / (O_ * C_);
        int rem = e % (O_ * C_);
        int o   = rem / C_;
        int c   = rem % C_;
        float v = w[((size_t)o * C_ + c) * KT + n];
        __hip_bfloat16 h = __float2bfloat16(v);
        wb[e] = *reinterpret_cast<unsigned short*>(&h);
    } else {
        int i = (bid - 13312) * 256 + threadIdx.x;    // i < 16*32*512 exactly
        int b = i / (32 * C_);
        int r = (i / C_) % 32;
        int c = i % C_;
        int tp = (r < 16) ? r : (T_ + r);             // [0,16) and [T_+16, T_+32)
        xt[((size_t)b * TP + tp) * C_ + c] = 0;
    }
}

// ---------------- conv-as-GEMM, R9 champion (byte-identical) ----------------
// Block tile 128(o) x 512(t), BK=32, 8 waves, wave tile 128x64 (1M x 8N).
// A: fragment-major LDS (zero-conflict). B: row-major [528][32], XOR slot swizzle.
// Per chunk: 5 phases {12 ds_read; 1-2 gload_lds prefetch; barrier; 32 MFMA}.
// No explicit lgkm drain (compiler emits counted lgkm waits). vmcnt(0) per chunk.
__global__ __launch_bounds__(512, 2) void conv_gemm_kernel(
        const unsigned short* __restrict__ wb,
        const unsigned short* __restrict__ xt,
        const float* __restrict__ bias,
        float* __restrict__ out) {
    __shared__ unsigned short a_lds[2][AFR * 512];   // 2 x 40960 B
    __shared__ unsigned short b_lds[2][BGR * 512];   // 2 x 33792 B

    // XCD-aware bijective swizzle (512 blocks): o-tile innermost.
    int bid = blockIdx.x;
    int swz = (bid & 7) * 64 + (bid >> 3);
    int o0  = (swz & 3) * BM;
    int t0  = ((swz >> 2) & 7) * BN;
    int b   = swz >> 5;

    int tid  = threadIdx.x;
    int lane = tid & 63;
    int wid  = tid >> 6;       // 0..7 = wave n-position
    int lr   = lane & 15;
    int lg   = lane >> 4;

    // chunk-invariant B read offsets (ushort units)
    int bo[KT][4];
#pragma unroll
    for (int n = 0; n < KT; ++n)
#pragma unroll
        for (int ni = 0; ni < 4; ++ni) {
            int row = wid * 64 + ni * 16 + lr + 4 - n;
            bo[n][ni] = row * 32 + ((lg ^ ((row >> 1) & 3)) << 3);
        }

    f32x4 acc[8][4];
#pragma unroll
    for (int mi = 0; mi < 8; ++mi)
#pragma unroll
        for (int ni = 0; ni < 4; ++ni)
            acc[mi][ni] = (f32x4)0.0f;

    // per-lane global staging bases
    const unsigned short* ag = wb + (size_t)(o0 + lr) * C_ + lg * 8;
    int c8 = (lane & 3) ^ ((lane >> 3) & 3);
    const unsigned short* bg = xt + ((size_t)b * TP + (t0 + 14 + (lane >> 2))) * C_ + c8 * 8;

    // ---- prologue: stage chunk 0 into buffer 0
#pragma unroll
    for (int f = wid; f < AFR; f += 8)
        gload_lds16(ag + (size_t)((f >> 3) * O_ + (f & 7) * 16) * C_, &a_lds[0][f * 512]);
#pragma unroll
    for (int j = wid; j < BGR; j += 8)
        gload_lds16(bg + (size_t)(j * 16) * C_, &b_lds[0][j * 512]);
    asm volatile("s_waitcnt vmcnt(0)" ::: "memory");
    __builtin_amdgcn_s_barrier();

    for (int chunk = 0; chunk < NCHUNK; ++chunk) {
        int cur = chunk & 1;
        int c1  = (chunk + 1) * BK;
        bool pf = (chunk + 1 < NCHUNK);

#pragma unroll
        for (int n = 0; n < KT; ++n) {
            // ---- phase n: read tap n's fragments
            short8 af[8], bf[4];
#pragma unroll
            for (int mi = 0; mi < 8; ++mi)
                af[mi] = *reinterpret_cast<const short8*>(
                    &a_lds[cur][(n * 8 + mi) * 512 + lane * 8]);
#pragma unroll
            for (int ni = 0; ni < 4; ++ni)
                bf[ni] = *reinterpret_cast<const short8*>(&b_lds[cur][bo[n][ni]]);

            // ---- prefetch slice for chunk+1 (1 A group + <=1 B group per wave)
            if (pf) {
                int f = n * 8 + wid;
                gload_lds16(ag + (size_t)((f >> 3) * O_ + (f & 7) * 16) * C_ + c1,
                            &a_lds[cur ^ 1][f * 512]);
                int j = n * 8 + wid;
                if (j < BGR)
                    gload_lds16(bg + (size_t)(j * 16) * C_ + c1, &b_lds[cur ^ 1][j * 512]);
            }

            __builtin_amdgcn_s_barrier();
            // no lgkmcnt(0): compiler interleaves counted lgkm waits.

            __builtin_amdgcn_s_setprio(1);
#pragma unroll
            for (int mi = 0; mi < 8; ++mi)
#pragma unroll
                for (int ni = 0; ni < 4; ++ni)
                    acc[mi][ni] = __builtin_amdgcn_mfma_f32_16x16x32_bf16(
                        af[mi], bf[ni], acc[mi][ni], 0, 0, 0);
            __builtin_amdgcn_s_setprio(0);
        }

        // ---- chunk boundary: ensure next buffer fully staged on all waves
        asm volatile("s_waitcnt vmcnt(0)" ::: "memory");
        __builtin_amdgcn_s_barrier();
    }

    // ---- epilogue: C/D layout col=lane&15, row=(lane>>4)*4+reg
#pragma unroll
    for (int mi = 0; mi < 8; ++mi) {
#pragma unroll
        for (int ni = 0; ni < 4; ++ni) {
            int orow = o0 + mi * 16 + lg * 4;
            int tcol = t0 + wid * 64 + ni * 16 + lr;
#pragma unroll
            for (int r = 0; r < 4; ++r) {
                out[((size_t)b * O_ + orow + r) * T_ + tcol] =
                    acc[mi][ni][r] + bias[orow + r];
            }
        }
    }
}

extern "C" void kernel_launch(void* const* d_in, const int* in_sizes, int n_in,
                              void* d_out, int out_size, void* d_ws, size_t ws_size,
                              hipStream_t stream) {
    const float* x    = (const float*)d_in[0];
    const float* w    = (const float*)d_in[1];
    const float* bias = (const float*)d_in[2];
    float* out        = (float*)d_out;

    unsigned short* wb  = (unsigned short*)d_ws;            // 2.62 MB
    unsigned short* xtp = wb + (size_t)KT * O_ * C_;        // 16*4128*512 bf16 = 67.7 MB

    pre_kernel<<<14336, 256, 0, stream>>>(x, w, wb, xtp);
    conv_gemm_kernel<<<512, 512, 0, stream>>>(wb, xtp, bias, out);
}